// Round 7
// baseline (158.019 us; speedup 1.0000x reference)
//
#include <hip/hip_runtime.h>
#include <math.h>

#define NPTS 4096
#define NV   3200
#define NF   6240
#define PB   8
#define FS   6272           // face SoA stride (multiple of 64)
#define SLOT 9              // u64 stride per 8-key list (pad kills bank alias)
#define SENT 0xFFFFFFFFFFFFFFFFull

__device__ __forceinline__ float sane(float v) {
    return (v == v && fabsf(v) < 1e30f) ? v : 0.0f;
}

// merge two sorted-ascending 8-lists (LDS) -> smallest 8, sorted, into dst.
__device__ __forceinline__ void merge8(const unsigned long long* __restrict__ a,
                                       const unsigned long long* __restrict__ b,
                                       unsigned long long* __restrict__ d) {
    unsigned long long L[8];
#pragma unroll
    for (int i = 0; i < 8; ++i) {
        const unsigned long long x = a[i], y = b[7 - i];
        L[i] = (x < y) ? x : y;
    }
#pragma unroll
    for (int dist = 4; dist >= 1; dist >>= 1) {
#pragma unroll
        for (int i = 0; i < 8; ++i) {
            if ((i & dist) == 0) {
                const unsigned long long lo = L[i], hi = L[i + dist];
                const bool sw = hi < lo;
                L[i]        = sw ? hi : lo;
                L[i + dist] = sw ? lo : hi;
            }
        }
    }
#pragma unroll
    for (int i = 0; i < 8; ++i) d[i] = L[i];
}

// ---------------- Kernel A: KNN + blended normal ------------------------------
// grid 1024 x 256. Verts staged fp32 in LDS (coalesced float4); distance loop
// reads LDS (2-way bank alias = free). Merge buffers ALIAS the verts LDS after
// a barrier (38.4 KB total). Math identical to round 6 -> bit-exact normals.
__global__ __launch_bounds__(256) void normals_kernel(
    const float* __restrict__ x_in,
    const float* __restrict__ verts,
    const float* __restrict__ vnorm,
    float* __restrict__ out)     // d_out: [xc 12288][s 4096][n 12288] fp32
{
#pragma clang fp contract(off)
    __shared__ __align__(16) float lv[NV * 3];     // 38.4 KB, aliased below
    const int tid  = threadIdx.x;
    const int wid  = tid >> 6;
    const int lane = tid & 63;
    const int p    = blockIdx.x * 4 + wid;

    // coalesced staging: 9600 floats = 2400 float4
    {
        const float4* __restrict__ v4 = (const float4*)verts;
        float4* __restrict__ l4 = (float4*)lv;
        for (int i = tid; i < NV * 3 / 4; i += 256) l4[i] = v4[i];
    }
    __syncthreads();

    const float px = x_in[3 * p + 0];
    const float py = x_in[3 * p + 1];
    const float pz = x_in[3 * p + 2];

    unsigned long long top[8];
#pragma unroll
    for (int k = 0; k < 8; ++k) top[k] = SENT;

    for (int j = 0; j < NV / 64; ++j) {
        const int v = lane + (j << 6);
        const float dx = px - lv[3 * v + 0];
        const float dy = py - lv[3 * v + 1];
        const float dz = pz - lv[3 * v + 2];
        const float d2 = dx * dx + dy * dy + dz * dz;
        const unsigned long long key =
            ((unsigned long long)__float_as_uint(d2) << 32) | (unsigned int)v;
        if (key < top[7]) {
            top[7] = key;
#pragma unroll
            for (int k = 7; k > 0; --k)
                if (top[k] < top[k - 1]) {
                    unsigned long long t = top[k]; top[k] = top[k - 1]; top[k - 1] = t;
                }
        }
    }
    __syncthreads();   // all waves done reading lv -> safe to alias

    unsigned long long* __restrict__ bufA = (unsigned long long*)&lv[0];
    unsigned long long* __restrict__ bufB = (unsigned long long*)&lv[4608];
    unsigned long long* __restrict__ A = bufA + wid * 64 * SLOT;
    unsigned long long* __restrict__ B = bufB + wid * 32 * SLOT;
#pragma unroll
    for (int k = 0; k < 8; ++k) A[lane * SLOT + k] = top[k];
    __syncthreads();

    int n = 64;
    bool srcA = true;
    while (n > 1) {
        const int half = n >> 1;
        if (lane < half) {
            const unsigned long long* s = srcA ? A : B;
            unsigned long long*       d = srcA ? B : A;
            merge8(s + (2 * lane) * SLOT, s + (2 * lane + 1) * SLOT, d + lane * SLOT);
        }
        __syncthreads();
        srcA = !srcA;
        n = half;
    }

    if (lane == 0) {
        float tknx = 0.f, tkny = 0.f, tknz = 0.f, Wsum = 0.f;
#pragma unroll
        for (int k = 0; k < 8; ++k) {
            const unsigned long long key = A[k];
            const float d2 = __uint_as_float((unsigned int)(key >> 32));
            const int   vi = (int)(key & 0xFFFFFFFFull);
            const float w  = 1.0f / fmaxf(d2, 1e-8f);
            Wsum += w;
            tknx += vnorm[3 * vi + 0] * w;
            tkny += vnorm[3 * vi + 1] * w;
            tknz += vnorm[3 * vi + 2] * w;
        }
        const int v1 = (int)(A[0] & 0xFFFFFFFFull);
        const float rx = px - verts[3 * v1 + 0];   // global: lv is clobbered
        const float ry = py - verts[3 * v1 + 1];
        const float rz = pz - verts[3 * v1 + 2];
        const float d2v1 = fmaxf(rx * rx + ry * ry + rz * rz, 1e-8f);
        const float sc = 1.0f / (0.01f * d2v1);
        const float Wt = Wsum + 100.0f;
        const float ntx = (tknx + rx * sc) / Wt;
        const float nty = (tkny + ry * sc) / Wt;
        const float ntz = (tknz + rz * sc) / Wt;
        const float nrm = sqrtf(ntx * ntx + nty * nty + ntz * ntz);
        const float inv = 1.0f / (nrm + 1e-8f);
        out[NPTS * 4 + 3 * p + 0] = sane(ntx * inv);
        out[NPTS * 4 + 3 * p + 1] = sane(nty * inv);
        out[NPTS * 4 + 3 * p + 2] = sane(ntz * inv);
    }
}

// ---------------- Kernel P: per-face precompute -> d_ws SoA (13 x FS floats) --
// [0..2] v0, [3] c = N.v0, [4..6] N = e1 x e2, [7..9] U = (e2 x N)/(N.N),
// [10..12] V = (N x e1)/(N.N)
__global__ __launch_bounds__(256) void face_pre_kernel(
    const float* __restrict__ verts,
    const int* __restrict__ faces,
    float* __restrict__ fd)
{
    const int f = blockIdx.x * 256 + threadIdx.x;
    if (f >= NF) return;
    const int a = faces[3 * f + 0];
    const int b = faces[3 * f + 1];
    const int c = faces[3 * f + 2];
    const float v0x = verts[3 * a + 0], v0y = verts[3 * a + 1], v0z = verts[3 * a + 2];
    const float e1x = verts[3 * b + 0] - v0x;
    const float e1y = verts[3 * b + 1] - v0y;
    const float e1z = verts[3 * b + 2] - v0z;
    const float e2x = verts[3 * c + 0] - v0x;
    const float e2y = verts[3 * c + 1] - v0y;
    const float e2z = verts[3 * c + 2] - v0z;
    const float Nx = e1y * e2z - e1z * e2y;
    const float Ny = e1z * e2x - e1x * e2z;
    const float Nz = e1x * e2y - e1y * e2x;
    const float nn = Nx * Nx + Ny * Ny + Nz * Nz;
    const float rnn = (nn > 0.0f) ? (1.0f / nn) : 0.0f;
    const float Ux = (e2y * Nz - e2z * Ny) * rnn;
    const float Uy = (e2z * Nx - e2x * Nz) * rnn;
    const float Uz = (e2x * Ny - e2y * Nx) * rnn;
    const float Vx = (Ny * e1z - Nz * e1y) * rnn;
    const float Vy = (Nz * e1x - Nx * e1z) * rnn;
    const float Vz = (Nx * e1y - Ny * e1x) * rnn;
    fd[ 0 * FS + f] = v0x; fd[ 1 * FS + f] = v0y; fd[ 2 * FS + f] = v0z;
    fd[ 3 * FS + f] = Nx * v0x + Ny * v0y + Nz * v0z;
    fd[ 4 * FS + f] = Nx;  fd[ 5 * FS + f] = Ny;  fd[ 6 * FS + f] = Nz;
    fd[ 7 * FS + f] = Ux;  fd[ 8 * FS + f] = Uy;  fd[ 9 * FS + f] = Uz;
    fd[10 * FS + f] = Vx;  fd[11 * FS + f] = Vy;  fd[12 * FS + f] = Vz;
}

// ---------------- Kernel B-fast: raycast from face SoA ------------------------
// t = (c - N.o)/(N.d); P-v0 = (o-v0) + t d; u = w.U, v = w.V. 13 coalesced
// loads per face amortized over 8 points. FP contraction ON (default).
__global__ __launch_bounds__(256) void raycast_fast_kernel(
    const float* __restrict__ x_in,
    const float* __restrict__ fd,
    float* __restrict__ out)
{
    __shared__ float sx[PB][3];
    __shared__ float sn[PB][3];
    __shared__ float red[PB * 256];
    const int tid = threadIdx.x;
    const int p0  = blockIdx.x * PB;

    if (tid < PB * 3) {
        const int p = tid / 3, c = tid % 3;
        sx[p][c] = x_in[(p0 + p) * 3 + c];
        sn[p][c] = out[NPTS * 4 + (p0 + p) * 3 + c];
    }
    __syncthreads();

    float qx[PB], qy[PB], qz[PB], dx[PB], dy[PB], dz[PB], tmin[PB];
#pragma unroll
    for (int p = 0; p < PB; ++p) {
        qx[p] = sx[p][0]; qy[p] = sx[p][1]; qz[p] = sx[p][2];
        dx[p] = -sn[p][0]; dy[p] = -sn[p][1]; dz[p] = -sn[p][2];
        tmin[p] = 3.0e38f;
    }

    for (int f = tid; f < NF; f += 256) {
        const float v0x = fd[ 0 * FS + f], v0y = fd[ 1 * FS + f], v0z = fd[ 2 * FS + f];
        const float cc  = fd[ 3 * FS + f];
        const float Nx  = fd[ 4 * FS + f], Ny  = fd[ 5 * FS + f], Nz  = fd[ 6 * FS + f];
        const float Ux  = fd[ 7 * FS + f], Uy  = fd[ 8 * FS + f], Uz  = fd[ 9 * FS + f];
        const float Vx  = fd[10 * FS + f], Vy  = fd[11 * FS + f], Vz  = fd[12 * FS + f];
#pragma unroll
        for (int p = 0; p < PB; ++p) {
            const float dN = dx[p] * Nx + dy[p] * Ny + dz[p] * Nz;
            const float oN = qx[p] * Nx + qy[p] * Ny + qz[p] * Nz;
            const bool ok = fabsf(dN) > 1e-9f;
            const float rd = ok ? (1.0f / dN) : 0.0f;
            const float t  = (cc - oN) * rd;
            const float wx = (qx[p] - v0x) + t * dx[p];
            const float wy = (qy[p] - v0y) + t * dy[p];
            const float wz = (qz[p] - v0z) + t * dz[p];
            const float u  = wx * Ux + wy * Uy + wz * Uz;
            const float vv = wx * Vx + wy * Vy + wz * Vz;
            const bool valid = ok && (u >= -1e-6f) && (vv >= -1e-6f) &&
                               (u + vv <= 1.0f + 1e-6f) && (t > 1e-6f);
            if (valid) tmin[p] = fminf(tmin[p], t);
        }
    }

#pragma unroll
    for (int p = 0; p < PB; ++p) red[p * 256 + tid] = tmin[p];
    for (int s = 128; s > 0; s >>= 1) {
        __syncthreads();
        if (tid < s) {
#pragma unroll
            for (int p = 0; p < PB; ++p)
                red[p * 256 + tid] = fminf(red[p * 256 + tid], red[p * 256 + tid + s]);
        }
    }
    __syncthreads();

    if (tid < PB) {
        const int p = tid;
        const float m = red[p * 256];
        const float t = (m < 1e37f) ? m : 0.0f;
        const float px = sx[p][0], py = sx[p][1], pz = sx[p][2];
        const float nx = sn[p][0], ny = sn[p][1], nz = sn[p][2];
        const float xcx = px - t * nx;
        const float xcy = py - t * ny;
        const float xcz = pz - t * nz;
        const float sdot = (px - xcx) * nx + (py - xcy) * ny + (pz - xcz) * nz;
        const int gp = p0 + p;
        out[3 * gp + 0] = sane(xcx);
        out[3 * gp + 1] = sane(xcy);
        out[3 * gp + 2] = sane(xcz);
        out[NPTS * 3 + gp] = sane(sdot);
    }
}

// ---------------- Kernel B-fallback: round-6 raycast (no d_ws) ----------------
__global__ __launch_bounds__(256) void raycast_kernel(
    const float* __restrict__ x_in,
    const float* __restrict__ verts,
    const int* __restrict__ faces,
    float* __restrict__ out)
{
#pragma clang fp contract(off)
    __shared__ float sx[PB][3];
    __shared__ float sn[PB][3];
    __shared__ float red[PB * 256];
    const int tid = threadIdx.x;
    const int p0  = blockIdx.x * PB;

    if (tid < PB * 3) {
        const int p = tid / 3, c = tid % 3;
        sx[p][c] = x_in[(p0 + p) * 3 + c];
        sn[p][c] = out[NPTS * 4 + (p0 + p) * 3 + c];
    }
    __syncthreads();

    float qx[PB], qy[PB], qz[PB], dx[PB], dy[PB], dz[PB], tmin[PB];
#pragma unroll
    for (int p = 0; p < PB; ++p) {
        qx[p] = sx[p][0]; qy[p] = sx[p][1]; qz[p] = sx[p][2];
        dx[p] = -sn[p][0]; dy[p] = -sn[p][1]; dz[p] = -sn[p][2];
        tmin[p] = 3.0e38f;
    }

    for (int f = tid; f < NF; f += 256) {
        const int a = faces[3 * f + 0];
        const int b = faces[3 * f + 1];
        const int c = faces[3 * f + 2];
        const float v0x = verts[3 * a + 0];
        const float v0y = verts[3 * a + 1];
        const float v0z = verts[3 * a + 2];
        const float e1x = verts[3 * b + 0] - v0x;
        const float e1y = verts[3 * b + 1] - v0y;
        const float e1z = verts[3 * b + 2] - v0z;
        const float e2x = verts[3 * c + 0] - v0x;
        const float e2y = verts[3 * c + 1] - v0y;
        const float e2z = verts[3 * c + 2] - v0z;
#pragma unroll
        for (int p = 0; p < PB; ++p) {
            const float pvx = dy[p] * e2z - dz[p] * e2y;
            const float pvy = dz[p] * e2x - dx[p] * e2z;
            const float pvz = dx[p] * e2y - dy[p] * e2x;
            const float det = e1x * pvx + e1y * pvy + e1z * pvz;
            const bool ok = fabsf(det) > 1e-9f;
            const float det_s = ok ? det : 1.0f;
            const float invd = ok ? (1.0f / det_s) : 0.0f;
            const float tvx = qx[p] - v0x;
            const float tvy = qy[p] - v0y;
            const float tvz = qz[p] - v0z;
            const float u = (tvx * pvx + tvy * pvy + tvz * pvz) * invd;
            const float qvx = tvy * e1z - tvz * e1y;
            const float qvy = tvz * e1x - tvx * e1z;
            const float qvz = tvx * e1y - tvy * e1x;
            const float vv = (dx[p] * qvx + dy[p] * qvy + dz[p] * qvz) * invd;
            const float tt = (e2x * qvx + e2y * qvy + e2z * qvz) * invd;
            const bool valid = ok && (u >= -1e-6f) && (vv >= -1e-6f) &&
                               (u + vv <= 1.0f + 1e-6f) && (tt > 1e-6f);
            if (valid) tmin[p] = fminf(tmin[p], tt);
        }
    }

#pragma unroll
    for (int p = 0; p < PB; ++p) red[p * 256 + tid] = tmin[p];
    for (int s = 128; s > 0; s >>= 1) {
        __syncthreads();
        if (tid < s) {
#pragma unroll
            for (int p = 0; p < PB; ++p)
                red[p * 256 + tid] = fminf(red[p * 256 + tid], red[p * 256 + tid + s]);
        }
    }
    __syncthreads();

    if (tid < PB) {
        const int p = tid;
        const float m = red[p * 256];
        const float t = (m < 1e37f) ? m : 0.0f;
        const float px = sx[p][0], py = sx[p][1], pz = sx[p][2];
        const float nx = sn[p][0], ny = sn[p][1], nz = sn[p][2];
        const float xcx = px - t * nx;
        const float xcy = py - t * ny;
        const float xcz = pz - t * nz;
        const float sdot = (px - xcx) * nx + (py - xcy) * ny + (pz - xcz) * nz;
        const int gp = p0 + p;
        out[3 * gp + 0] = sane(xcx);
        out[3 * gp + 1] = sane(xcy);
        out[3 * gp + 2] = sane(xcz);
        out[NPTS * 3 + gp] = sane(sdot);
    }
}

extern "C" void kernel_launch(void* const* d_in, const int* in_sizes, int n_in,
                              void* d_out, int out_size, void* d_ws, size_t ws_size,
                              hipStream_t stream) {
    const float* x     = (const float*)d_in[0];
    const float* verts = (const float*)d_in[1];
    const float* vnorm = (const float*)d_in[2];
    const int*   faces = (const int*)d_in[3];
    float* out = (float*)d_out;

    normals_kernel<<<NPTS / 4, 256, 0, stream>>>(x, verts, vnorm, out);

    const size_t FD_BYTES = (size_t)13 * FS * sizeof(float);   // ~326 KB
    if (ws_size >= FD_BYTES) {
        float* fd = (float*)d_ws;
        face_pre_kernel<<<(NF + 255) / 256, 256, 0, stream>>>(verts, faces, fd);
        raycast_fast_kernel<<<NPTS / PB, 256, 0, stream>>>(x, fd, out);
    } else {
        raycast_kernel<<<NPTS / PB, 256, 0, stream>>>(x, verts, faces, out);
    }
}

// Round 9
// 152.485 us; speedup vs baseline: 1.0363x; 1.0363x over previous
//
#include <hip/hip_runtime.h>
#include <math.h>

#define NPTS 4096
#define NV   3200
#define NF   6240
#define PB   8              // points per block
#define SLOT 9              // u64 stride per 8-key list (pad kills bank alias)
#define SENT 0xFFFFFFFFFFFFFFFFull

typedef unsigned long long ull;

__device__ __forceinline__ float sane(float v) {
    return (v == v && fabsf(v) < 1e30f) ? v : 0.0f;
}

// merge two sorted-ascending 8-lists (LDS) -> smallest 8, sorted, into dst.
__device__ __forceinline__ void merge8(const ull* __restrict__ a,
                                       const ull* __restrict__ b,
                                       ull* __restrict__ d) {
    ull L[8];
#pragma unroll
    for (int i = 0; i < 8; ++i) {
        const ull x = a[i], y = b[7 - i];
        L[i] = (x < y) ? x : y;
    }
#pragma unroll
    for (int dist = 4; dist >= 1; dist >>= 1) {
#pragma unroll
        for (int i = 0; i < 8; ++i) {
            if ((i & dist) == 0) {
                const ull lo = L[i], hi = L[i + dist];
                const bool sw = hi < lo;
                L[i]        = sw ? hi : lo;
                L[i + dist] = sw ? lo : hi;
            }
        }
    }
#pragma unroll
    for (int i = 0; i < 8; ++i) d[i] = L[i];
}

// ---------------- Fused kernel: KNN+normal then raycast -----------------------
// grid 512 x 256. Block owns 8 points.
// Phase 1 (bit-exact vs numpy ref, fp contract OFF): wave w computes points
//   w*2, w*2+1 via per-lane sorted top-8 over 50 global verts + LDS bitonic
//   merge tree.
// Phase 2 (contract ON): stage verts fp32 -> LDS (aliasing the merge buffers),
//   per-thread reciprocal-basis precompute per face, 21-op test vs 8 points.
__global__ __launch_bounds__(256) void fused_kernel(
    const float* __restrict__ x_in,
    const float* __restrict__ verts,
    const float* __restrict__ vnorm,
    const int* __restrict__ faces,
    float* __restrict__ out)     // d_out: [xc 12288][s 4096][n 12288] fp32
{
    // ---- hand-managed LDS ----
    // [0, 18432)      phase 1: merge A (4 waves x 64 lists x SLOT u64)
    // [18432, 27648)  phase 1: merge B (4 waves x 32 lists x SLOT u64)
    // [0, 38400)      phase 2: lv (9600 floats)          <- aliases A+B
    // [38400, 46592)  red (2048 floats)
    // [46592, 46784)  sx[8][3], sn[8][3]
    __shared__ __align__(16) unsigned char smem[46784];
    ull*   mA  = (ull*)smem;
    ull*   mB  = (ull*)(smem + 18432);
    float* lv  = (float*)smem;
    float* red = (float*)(smem + 38400);
    float* sx  = (float*)(smem + 46592);          // [8][3]
    float* sn  = (float*)(smem + 46592 + 96);     // [8][3]

    const int tid  = threadIdx.x;
    const int wid  = tid >> 6;
    const int lane = tid & 63;
    const int p0   = blockIdx.x * PB;

    if (tid < PB * 3) sx[tid] = x_in[p0 * 3 + tid];
    __syncthreads();

    ull* __restrict__ A = mA + wid * 64 * SLOT;
    ull* __restrict__ B = mB + wid * 32 * SLOT;

    // ================= Phase 1: KNN + blended normal (2 pts per wave) =========
    {
#pragma clang fp contract(off)
        for (int sub = 0; sub < 2; ++sub) {
            const int lp = wid * 2 + sub;
            const int p  = p0 + lp;
            const float px = sx[lp * 3 + 0];
            const float py = sx[lp * 3 + 1];
            const float pz = sx[lp * 3 + 2];

            ull top[8];
#pragma unroll
            for (int k = 0; k < 8; ++k) top[k] = SENT;

            for (int j = 0; j < NV / 64; ++j) {
                const int v = lane + (j << 6);
                const float dx = px - verts[3 * v + 0];
                const float dy = py - verts[3 * v + 1];
                const float dz = pz - verts[3 * v + 2];
                const float d2 = dx * dx + dy * dy + dz * dz;
                const ull key = ((ull)__float_as_uint(d2) << 32) | (unsigned int)v;
                if (key < top[7]) {
                    top[7] = key;
#pragma unroll
                    for (int k = 7; k > 0; --k)
                        if (top[k] < top[k - 1]) {
                            ull t = top[k]; top[k] = top[k - 1]; top[k - 1] = t;
                        }
                }
            }

#pragma unroll
            for (int k = 0; k < 8; ++k) A[lane * SLOT + k] = top[k];
            __syncthreads();

            int n = 64;
            bool srcA = true;
            while (n > 1) {
                const int half = n >> 1;
                if (lane < half) {
                    const ull* s = srcA ? A : B;
                    ull*       d = srcA ? B : A;
                    merge8(s + (2 * lane) * SLOT, s + (2 * lane + 1) * SLOT,
                           d + lane * SLOT);
                }
                __syncthreads();
                srcA = !srcA;
                n = half;
            }

            if (lane == 0) {
                float tknx = 0.f, tkny = 0.f, tknz = 0.f, Wsum = 0.f;
#pragma unroll
                for (int k = 0; k < 8; ++k) {
                    const ull key = A[k];
                    const float d2 = __uint_as_float((unsigned int)(key >> 32));
                    const int   vi = (int)(key & 0xFFFFFFFFull);
                    const float w  = 1.0f / fmaxf(d2, 1e-8f);
                    Wsum += w;
                    tknx += vnorm[3 * vi + 0] * w;
                    tkny += vnorm[3 * vi + 1] * w;
                    tknz += vnorm[3 * vi + 2] * w;
                }
                const int v1 = (int)(A[0] & 0xFFFFFFFFull);
                const float rx = px - verts[3 * v1 + 0];
                const float ry = py - verts[3 * v1 + 1];
                const float rz = pz - verts[3 * v1 + 2];
                const float d2v1 = fmaxf(rx * rx + ry * ry + rz * rz, 1e-8f);
                const float sc = 1.0f / (0.01f * d2v1);
                const float Wt = Wsum + 100.0f;
                const float ntx = (tknx + rx * sc) / Wt;
                const float nty = (tkny + ry * sc) / Wt;
                const float ntz = (tknz + rz * sc) / Wt;
                const float nrm = sqrtf(ntx * ntx + nty * nty + ntz * ntz);
                const float inv = 1.0f / (nrm + 1e-8f);
                const float nx = ntx * inv, ny = nty * inv, nz = ntz * inv;
                sn[lp * 3 + 0] = nx; sn[lp * 3 + 1] = ny; sn[lp * 3 + 2] = nz;
                out[NPTS * 4 + 3 * p + 0] = sane(nx);
                out[NPTS * 4 + 3 * p + 1] = sane(ny);
                out[NPTS * 4 + 3 * p + 2] = sane(nz);
            }
            __syncthreads();   // A region must be free before next sub-iteration
        }
    }

    // ================= Phase 2: raycast =======================================
    // stage verts -> lv (aliases merge region; all merges done)
    {
        const float4* __restrict__ v4 = (const float4*)verts;
        float4* __restrict__ l4 = (float4*)lv;
        for (int i = tid; i < NV * 3 / 4; i += 256) l4[i] = v4[i];
    }
    __syncthreads();

    float qx[PB], qy[PB], qz[PB], dxr[PB], dyr[PB], dzr[PB], tmin[PB];
#pragma unroll
    for (int p = 0; p < PB; ++p) {
        qx[p] = sx[p * 3 + 0]; qy[p] = sx[p * 3 + 1]; qz[p] = sx[p * 3 + 2];
        dxr[p] = -sn[p * 3 + 0]; dyr[p] = -sn[p * 3 + 1]; dzr[p] = -sn[p * 3 + 2];
        tmin[p] = 3.0e38f;
    }

    for (int f = tid; f < NF; f += 256) {
        const int a = faces[3 * f + 0];
        const int b = faces[3 * f + 1];
        const int c = faces[3 * f + 2];
        const float v0x = lv[3 * a + 0], v0y = lv[3 * a + 1], v0z = lv[3 * a + 2];
        const float e1x = lv[3 * b + 0] - v0x;
        const float e1y = lv[3 * b + 1] - v0y;
        const float e1z = lv[3 * b + 2] - v0z;
        const float e2x = lv[3 * c + 0] - v0x;
        const float e2y = lv[3 * c + 1] - v0y;
        const float e2z = lv[3 * c + 2] - v0z;
        // reciprocal basis: N = e1 x e2, U = (e2 x N)/N.N, V = (N x e1)/N.N
        const float Nx = e1y * e2z - e1z * e2y;
        const float Ny = e1z * e2x - e1x * e2z;
        const float Nz = e1x * e2y - e1y * e2x;
        const float nn = Nx * Nx + Ny * Ny + Nz * Nz;
        const float rnn = (nn > 0.0f) ? (1.0f / nn) : 0.0f;
        const float Ux = (e2y * Nz - e2z * Ny) * rnn;
        const float Uy = (e2z * Nx - e2x * Nz) * rnn;
        const float Uz = (e2x * Ny - e2y * Nx) * rnn;
        const float Vx = (Ny * e1z - Nz * e1y) * rnn;
        const float Vy = (Nz * e1x - Nx * e1z) * rnn;
        const float Vz = (Nx * e1y - Ny * e1x) * rnn;
        const float cc = Nx * v0x + Ny * v0y + Nz * v0z;
#pragma unroll
        for (int p = 0; p < PB; ++p) {
            const float dN = dxr[p] * Nx + dyr[p] * Ny + dzr[p] * Nz;  // = -det
            const float oN = qx[p] * Nx + qy[p] * Ny + qz[p] * Nz;
            const bool ok = fabsf(dN) > 1e-9f;
            const float rd = ok ? (1.0f / dN) : 0.0f;
            const float t  = (cc - oN) * rd;
            const float wx = (qx[p] - v0x) + t * dxr[p];
            const float wy = (qy[p] - v0y) + t * dyr[p];
            const float wz = (qz[p] - v0z) + t * dzr[p];
            const float u  = wx * Ux + wy * Uy + wz * Uz;
            const float vv = wx * Vx + wy * Vy + wz * Vz;
            const bool valid = ok && (u >= -1e-6f) && (vv >= -1e-6f) &&
                               (u + vv <= 1.0f + 1e-6f) && (t > 1e-6f);
            if (valid) tmin[p] = fminf(tmin[p], t);
        }
    }

#pragma unroll
    for (int p = 0; p < PB; ++p) red[p * 256 + tid] = tmin[p];
    for (int s = 128; s > 0; s >>= 1) {
        __syncthreads();
        if (tid < s) {
#pragma unroll
            for (int p = 0; p < PB; ++p)
                red[p * 256 + tid] = fminf(red[p * 256 + tid], red[p * 256 + tid + s]);
        }
    }
    __syncthreads();

    if (tid < PB) {
        const int p = tid;
        const float m = red[p * 256];
        const float t = (m < 1e37f) ? m : 0.0f;   // no hit -> t = 0 (matches ref)
        const float px = sx[p * 3 + 0], py = sx[p * 3 + 1], pz = sx[p * 3 + 2];
        const float nx = sn[p * 3 + 0], ny = sn[p * 3 + 1], nz = sn[p * 3 + 2];
        const float xcx = px - t * nx;
        const float xcy = py - t * ny;
        const float xcz = pz - t * nz;
        const float sdot = (px - xcx) * nx + (py - xcy) * ny + (pz - xcz) * nz;
        const int gp = p0 + p;
        out[3 * gp + 0] = sane(xcx);
        out[3 * gp + 1] = sane(xcy);
        out[3 * gp + 2] = sane(xcz);
        out[NPTS * 3 + gp] = sane(sdot);
    }
}

extern "C" void kernel_launch(void* const* d_in, const int* in_sizes, int n_in,
                              void* d_out, int out_size, void* d_ws, size_t ws_size,
                              hipStream_t stream) {
    const float* x     = (const float*)d_in[0];
    const float* verts = (const float*)d_in[1];
    const float* vnorm = (const float*)d_in[2];
    const int*   faces = (const int*)d_in[3];
    float* out = (float*)d_out;

    fused_kernel<<<NPTS / PB, 256, 0, stream>>>(x, verts, vnorm, faces, out);
}

// Round 10
// 135.859 us; speedup vs baseline: 1.1631x; 1.1224x over previous
//
#include <hip/hip_runtime.h>
#include <math.h>

#define NPTS 4096
#define NV   3200
#define NF   6240
#define PB   8              // points per block
#define NT   512            // threads per block (8 waves)
#define SLOT 9              // u64 stride per 8-key list (pad kills bank alias)
#define SENT 0xFFFFFFFFFFFFFFFFull

typedef unsigned long long ull;

__device__ __forceinline__ float sane(float v) {
    return (v == v && fabsf(v) < 1e30f) ? v : 0.0f;
}
__device__ __forceinline__ ull umin64(ull a, ull b) { return a < b ? a : b; }
__device__ __forceinline__ ull umax64(ull a, ull b) { return a > b ? a : b; }

// merge two sorted-ascending 8-lists (LDS) -> smallest 8, sorted, into dst.
__device__ __forceinline__ void merge8(const ull* __restrict__ a,
                                       const ull* __restrict__ b,
                                       ull* __restrict__ d) {
    ull L[8];
#pragma unroll
    for (int i = 0; i < 8; ++i) L[i] = umin64(a[i], b[7 - i]);
#pragma unroll
    for (int dist = 4; dist >= 1; dist >>= 1) {
#pragma unroll
        for (int i = 0; i < 8; ++i) {
            if ((i & dist) == 0) {
                const ull lo = L[i], hi = L[i + dist];
                L[i]        = umin64(lo, hi);
                L[i + dist] = umax64(lo, hi);
            }
        }
    }
#pragma unroll
    for (int i = 0; i < 8; ++i) d[i] = L[i];
}

// ---------------- Fused kernel, 512 threads ----------------------------------
// Phase 1 (contract OFF, bit-exact): wave w = point p0+w. 64 lanes x 50 verts,
//   branchless clamp-insert top-8 (u64 (d2,idx) keys = lax.top_k tie-break),
//   6-level LDS bitonic merge tree per wave.
// Phase 2 (contract ON): verts -> LDS (aliases merge bufs), reciprocal-basis
//   per-face precompute in registers, 8-point test, rcpf for divisions.
__global__ __launch_bounds__(NT, 4) void fused_kernel(
    const float* __restrict__ x_in,
    const float* __restrict__ verts,
    const float* __restrict__ vnorm,
    const int* __restrict__ faces,
    float* __restrict__ out)     // d_out: [xc 12288][s 4096][n 12288] fp32
{
    // ---- hand-managed LDS (55488 B static) ----
    // [0, 36864)       phase1: merge A (8 waves x 64 lists x SLOT u64)
    // [36864, 55296)   phase1: merge B (8 waves x 32 lists x SLOT u64)
    // [0, 38400)       phase2: lv (9600 floats)        <- aliases A+B
    // [38400, 54784)   phase2: red (PB*NT floats)      <- aliases B tail
    // [55296, 55488)   sx[8][3], sn[8][3]
    __shared__ __align__(16) unsigned char smem[55488];
    ull*   mA  = (ull*)smem;
    ull*   mB  = (ull*)(smem + 36864);
    float* lv  = (float*)smem;
    float* red = (float*)(smem + 38400);
    float* sx  = (float*)(smem + 55296);
    float* sn  = (float*)(smem + 55296 + 96);

    const int tid  = threadIdx.x;
    const int wid  = tid >> 6;
    const int lane = tid & 63;
    const int p0   = blockIdx.x * PB;

    if (tid < PB * 3) sx[tid] = x_in[p0 * 3 + tid];
    __syncthreads();

    ull* __restrict__ A = mA + wid * 64 * SLOT;
    ull* __restrict__ B = mB + wid * 32 * SLOT;

    // ================= Phase 1: KNN + blended normal (1 pt per wave) ==========
    {
#pragma clang fp contract(off)
        const int lp = wid;
        const int p  = p0 + lp;
        const float px = sx[lp * 3 + 0];
        const float py = sx[lp * 3 + 1];
        const float pz = sx[lp * 3 + 2];

        ull top[8];
#pragma unroll
        for (int k = 0; k < 8; ++k) top[k] = SENT;

        for (int j = 0; j < NV / 64; ++j) {
            const int v = lane + (j << 6);
            const float dx = px - verts[3 * v + 0];
            const float dy = py - verts[3 * v + 1];
            const float dz = pz - verts[3 * v + 2];
            const float d2 = dx * dx + dy * dy + dz * dz;
            const ull key = ((ull)__float_as_uint(d2) << 32) | (unsigned int)v;
            // branchless sorted insert: new[k] = min(old[k], max(old[k-1], key))
            ull prev = top[0];
            top[0] = umin64(top[0], key);
#pragma unroll
            for (int k = 1; k < 8; ++k) {
                const ull cur = top[k];
                top[k] = umin64(cur, umax64(prev, key));
                prev = cur;
            }
        }

#pragma unroll
        for (int k = 0; k < 8; ++k) A[lane * SLOT + k] = top[k];
        __syncthreads();

        int n = 64;
        bool srcA = true;
        while (n > 1) {
            const int half = n >> 1;
            if (lane < half) {
                const ull* s = srcA ? A : B;
                ull*       d = srcA ? B : A;
                merge8(s + (2 * lane) * SLOT, s + (2 * lane + 1) * SLOT,
                       d + lane * SLOT);
            }
            __syncthreads();
            srcA = !srcA;
            n = half;
        }
        // 6 levels (even) -> final list back in A[0..7]

        if (lane == 0) {
            float tknx = 0.f, tkny = 0.f, tknz = 0.f, Wsum = 0.f;
#pragma unroll
            for (int k = 0; k < 8; ++k) {
                const ull key = A[k];
                const float d2 = __uint_as_float((unsigned int)(key >> 32));
                const int   vi = (int)(key & 0xFFFFFFFFull);
                const float w  = 1.0f / fmaxf(d2, 1e-8f);
                Wsum += w;
                tknx += vnorm[3 * vi + 0] * w;
                tkny += vnorm[3 * vi + 1] * w;
                tknz += vnorm[3 * vi + 2] * w;
            }
            const int v1 = (int)(A[0] & 0xFFFFFFFFull);
            const float rx = px - verts[3 * v1 + 0];
            const float ry = py - verts[3 * v1 + 1];
            const float rz = pz - verts[3 * v1 + 2];
            const float d2v1 = fmaxf(rx * rx + ry * ry + rz * rz, 1e-8f);
            const float sc = 1.0f / (0.01f * d2v1);
            const float Wt = Wsum + 100.0f;
            const float ntx = (tknx + rx * sc) / Wt;
            const float nty = (tkny + ry * sc) / Wt;
            const float ntz = (tknz + rz * sc) / Wt;
            const float nrm = sqrtf(ntx * ntx + nty * nty + ntz * ntz);
            const float inv = 1.0f / (nrm + 1e-8f);
            const float nx = ntx * inv, ny = nty * inv, nz = ntz * inv;
            sn[lp * 3 + 0] = nx; sn[lp * 3 + 1] = ny; sn[lp * 3 + 2] = nz;
            out[NPTS * 4 + 3 * p + 0] = sane(nx);
            out[NPTS * 4 + 3 * p + 1] = sane(ny);
            out[NPTS * 4 + 3 * p + 2] = sane(nz);
        }
    }
    __syncthreads();     // all waves done with A before lv staging clobbers it

    // ================= Phase 2: raycast =======================================
    {
        const float4* __restrict__ v4 = (const float4*)verts;
        float4* __restrict__ l4 = (float4*)lv;
        for (int i = tid; i < NV * 3 / 4; i += NT) l4[i] = v4[i];
    }
    __syncthreads();

    float qx[PB], qy[PB], qz[PB], dxr[PB], dyr[PB], dzr[PB], tmin[PB];
#pragma unroll
    for (int p = 0; p < PB; ++p) {
        qx[p] = sx[p * 3 + 0]; qy[p] = sx[p * 3 + 1]; qz[p] = sx[p * 3 + 2];
        dxr[p] = -sn[p * 3 + 0]; dyr[p] = -sn[p * 3 + 1]; dzr[p] = -sn[p * 3 + 2];
        tmin[p] = 3.0e38f;
    }

    for (int f = tid; f < NF; f += NT) {
        const int a = faces[3 * f + 0];
        const int b = faces[3 * f + 1];
        const int c = faces[3 * f + 2];
        const float v0x = lv[3 * a + 0], v0y = lv[3 * a + 1], v0z = lv[3 * a + 2];
        const float e1x = lv[3 * b + 0] - v0x;
        const float e1y = lv[3 * b + 1] - v0y;
        const float e1z = lv[3 * b + 2] - v0z;
        const float e2x = lv[3 * c + 0] - v0x;
        const float e2y = lv[3 * c + 1] - v0y;
        const float e2z = lv[3 * c + 2] - v0z;
        const float Nx = e1y * e2z - e1z * e2y;
        const float Ny = e1z * e2x - e1x * e2z;
        const float Nz = e1x * e2y - e1y * e2x;
        const float nn = Nx * Nx + Ny * Ny + Nz * Nz;
        const float rnn = (nn > 0.0f) ? __builtin_amdgcn_rcpf(nn) : 0.0f;
        const float Ux = (e2y * Nz - e2z * Ny) * rnn;
        const float Uy = (e2z * Nx - e2x * Nz) * rnn;
        const float Uz = (e2x * Ny - e2y * Nx) * rnn;
        const float Vx = (Ny * e1z - Nz * e1y) * rnn;
        const float Vy = (Nz * e1x - Nx * e1z) * rnn;
        const float Vz = (Nx * e1y - Ny * e1x) * rnn;
        const float cc = Nx * v0x + Ny * v0y + Nz * v0z;
#pragma unroll
        for (int p = 0; p < PB; ++p) {
            const float dN = dxr[p] * Nx + dyr[p] * Ny + dzr[p] * Nz;
            const float oN = qx[p] * Nx + qy[p] * Ny + qz[p] * Nz;
            const bool ok = fabsf(dN) > 1e-9f;
            const float rd = ok ? __builtin_amdgcn_rcpf(dN) : 0.0f;
            const float t  = (cc - oN) * rd;
            const float wx = (qx[p] - v0x) + t * dxr[p];
            const float wy = (qy[p] - v0y) + t * dyr[p];
            const float wz = (qz[p] - v0z) + t * dzr[p];
            const float u  = wx * Ux + wy * Uy + wz * Uz;
            const float vv = wx * Vx + wy * Vy + wz * Vz;
            const bool valid = ok && (u >= -1e-6f) && (vv >= -1e-6f) &&
                               (u + vv <= 1.0f + 1e-6f) && (t > 1e-6f);
            if (valid) tmin[p] = fminf(tmin[p], t);
        }
    }

#pragma unroll
    for (int p = 0; p < PB; ++p) red[p * NT + tid] = tmin[p];
    for (int s = NT / 2; s > 0; s >>= 1) {
        __syncthreads();
        if (tid < s) {
#pragma unroll
            for (int p = 0; p < PB; ++p)
                red[p * NT + tid] = fminf(red[p * NT + tid], red[p * NT + tid + s]);
        }
    }
    __syncthreads();

    if (tid < PB) {
        const int p = tid;
        const float m = red[p * NT];
        const float t = (m < 1e37f) ? m : 0.0f;   // no hit -> t = 0 (matches ref)
        const float px = sx[p * 3 + 0], py = sx[p * 3 + 1], pz = sx[p * 3 + 2];
        const float nx = sn[p * 3 + 0], ny = sn[p * 3 + 1], nz = sn[p * 3 + 2];
        const float xcx = px - t * nx;
        const float xcy = py - t * ny;
        const float xcz = pz - t * nz;
        const float sdot = (px - xcx) * nx + (py - xcy) * ny + (pz - xcz) * nz;
        const int gp = p0 + p;
        out[3 * gp + 0] = sane(xcx);
        out[3 * gp + 1] = sane(xcy);
        out[3 * gp + 2] = sane(xcz);
        out[NPTS * 3 + gp] = sane(sdot);
    }
}

extern "C" void kernel_launch(void* const* d_in, const int* in_sizes, int n_in,
                              void* d_out, int out_size, void* d_ws, size_t ws_size,
                              hipStream_t stream) {
    const float* x     = (const float*)d_in[0];
    const float* verts = (const float*)d_in[1];
    const float* vnorm = (const float*)d_in[2];
    const int*   faces = (const int*)d_in[3];
    float* out = (float*)d_out;

    fused_kernel<<<NPTS / PB, NT, 0, stream>>>(x, verts, vnorm, faces, out);
}